// Round 1
// baseline (612.399 us; speedup 1.0000x reference)
//
#include <hip/hip_runtime.h>

#define NUM_LAYERS 10
#define HIDDEN 5
#define SEQ 457
#define BATCH 4096
#define OUT_DIM 457
#define KDIM (SEQ * HIDDEN)   // 2285

#define G_PER_BLOCK 16
#define LSTM_THREADS (NUM_LAYERS * G_PER_BLOCK * HIDDEN)  // 800

__device__ __forceinline__ float frcp(float x) { return __builtin_amdgcn_rcpf(x); }
__device__ __forceinline__ float sigm(float x) { return frcp(1.0f + __expf(-x)); }
__device__ __forceinline__ float tanh_(float x) { return 1.0f - 2.0f * frcp(1.0f + __expf(2.0f * x)); }

// Pipelined 10-layer LSTM: layer l at global step s processes timestep t = s - l.
// Inter-layer h values flow through a double-buffered LDS slab; one barrier/step.
__global__ __launch_bounds__(LSTM_THREADS) void lstm_kernel(
    const float* __restrict__ x,      // [B][SEQ][5]
    const float* __restrict__ W_ih,   // [10][20][5]
    const float* __restrict__ W_hh,   // [10][20][5]
    const float* __restrict__ b_ih,   // [10][20]
    const float* __restrict__ b_hh,   // [10][20]
    float* __restrict__ Hout)         // [KDIM][BATCH]: Hout[(t*5+j)*BATCH + b]
{
    const int tid = threadIdx.x;
    const int j = tid % HIDDEN;
    const int g = (tid / HIDDEN) % G_PER_BLOCK;
    const int l = tid / (HIDDEN * G_PER_BLOCK);
    const int b = blockIdx.x * G_PER_BLOCK + g;

    // Per-thread weights -> registers (rows j, 5+j, 10+j, 15+j of layer l)
    float wih[4][5], whh[4][5], bb[4];
#pragma unroll
    for (int q = 0; q < 4; ++q) {
        const int row = q * HIDDEN + j;
#pragma unroll
        for (int i = 0; i < 5; ++i) {
            wih[q][i] = W_ih[(l * 20 + row) * 5 + i];
            whh[q][i] = W_hh[(l * 20 + row) * 5 + i];
        }
        bb[q] = b_ih[l * 20 + row] + b_hh[l * 20 + row];
    }

    __shared__ float hbuf[2][NUM_LAYERS][G_PER_BLOCK][HIDDEN];
    for (int idx = tid; idx < 2 * NUM_LAYERS * G_PER_BLOCK * HIDDEN; idx += blockDim.x)
        ((float*)hbuf)[idx] = 0.0f;
    __syncthreads();

    float c = 0.0f;
    int p = 0;
    const float* xb = x + (size_t)b * (SEQ * HIDDEN);

    for (int s = 0; s < SEQ + NUM_LAYERS - 1; ++s) {
        const int t = s - l;
        const bool active = (t >= 0) && (t < SEQ);
        if (active) {
            float in[5], hp[5];
            if (l == 0) {
#pragma unroll
                for (int i = 0; i < 5; ++i) in[i] = xb[t * 5 + i];
            } else {
#pragma unroll
                for (int i = 0; i < 5; ++i) in[i] = hbuf[p][l - 1][g][i];
            }
#pragma unroll
            for (int i = 0; i < 5; ++i) hp[i] = hbuf[p][l][g][i];

            float gate[4];
#pragma unroll
            for (int q = 0; q < 4; ++q) {
                float a = bb[q];
#pragma unroll
                for (int i = 0; i < 5; ++i) a = fmaf(wih[q][i], in[i], a);
#pragma unroll
                for (int i = 0; i < 5; ++i) a = fmaf(whh[q][i], hp[i], a);
                gate[q] = a;
            }
            const float ig = sigm(gate[0]);
            const float fg = sigm(gate[1]);
            const float gg = tanh_(gate[2]);
            const float og = sigm(gate[3]);
            c = fg * c + ig * gg;
            const float hj = og * tanh_(c);

            hbuf[1 - p][l][g][j] = hj;
            if (l == NUM_LAYERS - 1) {
                Hout[(size_t)(t * HIDDEN + j) * BATCH + b] = hj;
            }
        }
        __syncthreads();
        p ^= 1;
    }
}

// f32 tiled GEMM: out[b][o] = sum_k Hin[k][b] * fcW[o][k] + fcb[o]
#define BM 64
#define BN 64
#define BK 16

__global__ __launch_bounds__(256) void fc_kernel(
    const float* __restrict__ Hin,   // [KDIM][BATCH]
    const float* __restrict__ fcW,   // [OUT_DIM][KDIM]
    const float* __restrict__ fcb,   // [OUT_DIM]
    float* __restrict__ out)         // [BATCH][OUT_DIM]
{
    __shared__ float a_s[BK][BM];
    __shared__ float w_s[BK][BN];
    const int tid = threadIdx.x;
    const int bBase = blockIdx.x * BM;
    const int oBase = blockIdx.y * BN;

    const int tx = tid % 16;   // o sub-tile: tx*4..+3
    const int ty = tid / 16;   // b sub-tile: ty*4..+3
    float acc[4][4] = {};

    for (int k0 = 0; k0 < KDIM; k0 += BK) {
        // A tile: 16x64 floats, one float4 per thread, coalesced along b
        {
            const int idx = tid * 4;
            const int kk = idx / BM;
            const int bb2 = idx % BM;
            const int kg = k0 + kk;
            float4 v = make_float4(0.f, 0.f, 0.f, 0.f);
            if (kg < KDIM) v = *(const float4*)&Hin[(size_t)kg * BATCH + bBase + bb2];
            *(float4*)&a_s[kk][bb2] = v;
        }
        // W tile: 64 o x 16 k, 4 scalar k-loads per thread (rows are odd-length: no f4 align)
        {
            const int o = tid / 4;
            const int kq = (tid % 4) * 4;
            const int oo = oBase + o;
            float tmp[4] = {0.f, 0.f, 0.f, 0.f};
            if (oo < OUT_DIM) {
#pragma unroll
                for (int m = 0; m < 4; ++m) {
                    const int kg = k0 + kq + m;
                    if (kg < KDIM) tmp[m] = fcW[(size_t)oo * KDIM + kg];
                }
            }
            w_s[kq + 0][o] = tmp[0];
            w_s[kq + 1][o] = tmp[1];
            w_s[kq + 2][o] = tmp[2];
            w_s[kq + 3][o] = tmp[3];
        }
        __syncthreads();
#pragma unroll
        for (int kk = 0; kk < BK; ++kk) {
            const float4 av = *(const float4*)&a_s[kk][ty * 4];
            const float4 wv = *(const float4*)&w_s[kk][tx * 4];
            const float a4[4] = {av.x, av.y, av.z, av.w};
            const float w4[4] = {wv.x, wv.y, wv.z, wv.w};
#pragma unroll
            for (int bi = 0; bi < 4; ++bi)
#pragma unroll
                for (int oi = 0; oi < 4; ++oi)
                    acc[bi][oi] = fmaf(a4[bi], w4[oi], acc[bi][oi]);
        }
        __syncthreads();
    }

#pragma unroll
    for (int bi = 0; bi < 4; ++bi) {
        const int b = bBase + ty * 4 + bi;
#pragma unroll
        for (int oi = 0; oi < 4; ++oi) {
            const int o = oBase + tx * 4 + oi;
            if (o < OUT_DIM) out[(size_t)b * OUT_DIM + o] = acc[bi][oi] + fcb[o];
        }
    }
}

extern "C" void kernel_launch(void* const* d_in, const int* in_sizes, int n_in,
                              void* d_out, int out_size, void* d_ws, size_t ws_size,
                              hipStream_t stream) {
    const float* x    = (const float*)d_in[0];
    const float* W_ih = (const float*)d_in[3];
    const float* W_hh = (const float*)d_in[4];
    const float* b_ih = (const float*)d_in[5];
    const float* b_hh = (const float*)d_in[6];
    const float* fcW  = (const float*)d_in[7];
    const float* fcb  = (const float*)d_in[8];
    float* out = (float*)d_out;

    float* Hout = (float*)d_ws;   // KDIM * BATCH floats = 37.4 MB

    lstm_kernel<<<dim3(BATCH / G_PER_BLOCK), dim3(LSTM_THREADS), 0, stream>>>(
        x, W_ih, W_hh, b_ih, b_hh, Hout);

    dim3 fcGrid(BATCH / BM, (OUT_DIM + BN - 1) / BN);
    fc_kernel<<<fcGrid, dim3(256), 0, stream>>>(Hout, fcW, fcb, out);
}

// Round 3
// 593.986 us; speedup vs baseline: 1.0310x; 1.0310x over previous
//
#include <hip/hip_runtime.h>

#define NUM_LAYERS 10
#define HIDDEN 5
#define SEQ 457
#define BATCH 4096
#define OUT_DIM 457
#define KD 2285            // SEQ*HIDDEN
#define KPAD 2304          // 72 * 32, padded K for MFMA
#define NKT 72             // k-tiles of 32
#define OPAD 512           // padded OUT_DIM for unguarded B-frag loads

typedef __attribute__((ext_vector_type(8))) short short8;
typedef __attribute__((ext_vector_type(4))) float f32x4;

__device__ __forceinline__ float frcp(float x){ return __builtin_amdgcn_rcpf(x); }
__device__ __forceinline__ float sigm(float x){ return frcp(1.0f + __expf(-x)); }
__device__ __forceinline__ float tanh_(float x){ return 1.0f - 2.0f*frcp(1.0f + __expf(2.0f*x)); }
__device__ __forceinline__ unsigned short f2bf(float f){
    unsigned u = __float_as_uint(f);
    u = (u + 0x7FFFu + ((u>>16)&1u)) >> 16;
    return (unsigned short)u;
}
__device__ __forceinline__ float bf2f(unsigned short h){
    return __uint_as_float(((unsigned)h) << 16);
}

// ---------------------------------------------------------------------------
// LSTM: one wave = one batch element. lane = 5*layer + j (50 cell lanes).
// Lanes 50-54 = "ghost layer" feeding x into layer 0. Zero barriers; all
// inter-layer traffic is ds_bpermute on the per-lane h message register.
// Layer l at step s computes t = s - l; 466 steps total.
// ---------------------------------------------------------------------------
#define WAVES_PER_BLOCK 4
__global__ __launch_bounds__(64*WAVES_PER_BLOCK) void lstm_kernel(
    const float* __restrict__ x,      // [B][SEQ][5]
    const float* __restrict__ W_ih,   // [10][20][5]
    const float* __restrict__ W_hh,   // [10][20][5]
    const float* __restrict__ b_ih,   // [10][20]
    const float* __restrict__ b_hh,   // [10][20]
    unsigned short* __restrict__ Hb)  // bf16 [BATCH][KPAD]; Hb[b][t*5+j]
{
    const int lane = threadIdx.x & 63;
    const int wv = threadIdx.x >> 6;
    const int b = blockIdx.x * WAVES_PER_BLOCK + wv;
    const int l = lane / 5;
    const int j = lane - 5 * l;
    const bool isCell = lane < 50;
    const bool isGhost = (lane >= 50) && (lane < 55);
    const int lc = isCell ? l : 0;   // clamp for in-bounds weight loads

    unsigned short* Hrow = Hb + (size_t)b * KPAD;
    // zero the 19 pad columns of this batch row (ws is 0xAA-poisoned)
    if (lane < KPAD - KD) Hrow[KD + lane] = 0;

    // per-lane weights: rows q*5+j of layer l
    float wih[4][5], whh[4][5], bb[4];
#pragma unroll
    for (int q = 0; q < 4; ++q) {
        const int row = lc * 20 + q * HIDDEN + j;
#pragma unroll
        for (int i = 0; i < 5; ++i) {
            wih[q][i] = W_ih[row * 5 + i];
            whh[q][i] = W_hh[row * 5 + i];
        }
        bb[q] = b_ih[row] + b_hh[row];
    }

    // bpermute byte indices: own layer (for h_prev) and layer below (for input)
    const int baseH = 5 * l;
    const int baseI = (l == 0) ? 50 : (baseH - 5);
    int iH[5], iI[5];
#pragma unroll
    for (int i = 0; i < 5; ++i) { iH[i] = (baseH + i) * 4; iI[i] = (baseI + i) * 4; }

    const float* xb = x + (size_t)b * (SEQ * HIDDEN);

    float hmsg = 0.0f, c = 0.0f;
    float xv = 0.0f;
    if (isGhost) {
        hmsg = xb[lane - 50];            // x[t=0]
        xv   = xb[5 + (lane - 50)];      // x[t=1]
    }

    for (int s = 0; s < SEQ + NUM_LAYERS - 1; ++s) {
        const int hbits = __float_as_int(hmsg);
        float in[5], hp[5];
#pragma unroll
        for (int i = 0; i < 5; ++i)
            in[i] = __int_as_float(__builtin_amdgcn_ds_bpermute(iI[i], hbits));
#pragma unroll
        for (int i = 0; i < 5; ++i)
            hp[i] = __int_as_float(__builtin_amdgcn_ds_bpermute(iH[i], hbits));

        const int t = s - l;

        float g0 = bb[0], g1 = bb[1], g2 = bb[2], g3 = bb[3];
#pragma unroll
        for (int i = 0; i < 5; ++i) {
            g0 = fmaf(wih[0][i], in[i], g0);
            g1 = fmaf(wih[1][i], in[i], g1);
            g2 = fmaf(wih[2][i], in[i], g2);
            g3 = fmaf(wih[3][i], in[i], g3);
        }
#pragma unroll
        for (int i = 0; i < 5; ++i) {
            g0 = fmaf(whh[0][i], hp[i], g0);
            g1 = fmaf(whh[1][i], hp[i], g1);
            g2 = fmaf(whh[2][i], hp[i], g2);
            g3 = fmaf(whh[3][i], hp[i], g3);
        }
        const float ig = sigm(g0);
        const float fg = sigm(g1);
        const float gg = tanh_(g2);
        const float og = sigm(g3);

        if (isCell && t >= 0 && t < SEQ) {
            c = fg * c + ig * gg;
            const float h = og * tanh_(c);
            hmsg = h;
            if (l == NUM_LAYERS - 1) Hrow[t * 5 + j] = f2bf(h);
        }
        if (isGhost) {
            hmsg = xv;                               // x[s+1] for layer 0 next step
            int t2 = s + 2; if (t2 > SEQ - 1) t2 = SEQ - 1;
            xv = xb[t2 * 5 + (lane - 50)];
        }
    }
}

// ---------------------------------------------------------------------------
// fcW f32 -> bf16 hi/lo split, padded to [OPAD][KPAD] with zeros
// ---------------------------------------------------------------------------
__global__ __launch_bounds__(256) void convw_kernel(
    const float* __restrict__ fcW,
    unsigned short* __restrict__ Whi,
    unsigned short* __restrict__ Wlo)
{
    const int idx = blockIdx.x * 256 + threadIdx.x;
    if (idx >= OPAD * KPAD) return;
    const int o = idx / KPAD;
    const int k = idx - o * KPAD;
    float v = 0.0f;
    if (o < OUT_DIM && k < KD) v = fcW[o * KD + k];
    const unsigned short hi = f2bf(v);
    const float rem = v - bf2f(hi);
    Whi[idx] = hi;
    Wlo[idx] = f2bf(rem);
}

// ---------------------------------------------------------------------------
// FC: out[b][o] = sum_k H[b][k] * W[o][k] + fcb[o], bf16 MFMA, no LDS.
// Wave = 16 b-rows x 64 o-cols (4 B-frags); W split hi+lo -> 8 MFMA/k-iter.
// ---------------------------------------------------------------------------
__global__ __launch_bounds__(256) void fc_kernel(
    const unsigned short* __restrict__ Hb,    // [BATCH][KPAD] bf16
    const unsigned short* __restrict__ Whi,   // [OPAD][KPAD] bf16
    const unsigned short* __restrict__ Wlo,   // [OPAD][KPAD] bf16
    const float* __restrict__ fcb,            // [OUT_DIM]
    float* __restrict__ out)                  // [BATCH][OUT_DIM]
{
    const int lane = threadIdx.x & 63;
    const int w = threadIdx.x >> 6;
    const int b0 = blockIdx.x * 64 + w * 16;
    const int o0 = blockIdx.y * 64;
    const int row = lane & 15;          // A-row / B-col within 16
    const int kq = (lane >> 4) * 8;     // k sub-offset within 32-tile

    const unsigned short* Ha = Hb + (size_t)(b0 + row) * KPAD + kq;
    const unsigned short* Wh0 = Whi + (size_t)(o0 + row) * KPAD + kq;
    const unsigned short* Wl0 = Wlo + (size_t)(o0 + row) * KPAD + kq;

    f32x4 acc0 = {0.f, 0.f, 0.f, 0.f};
    f32x4 acc1 = {0.f, 0.f, 0.f, 0.f};
    f32x4 acc2 = {0.f, 0.f, 0.f, 0.f};
    f32x4 acc3 = {0.f, 0.f, 0.f, 0.f};

    for (int kk = 0; kk < NKT; ++kk) {
        const int kb = kk * 32;
        const short8 a = *(const short8*)(Ha + kb);

        const short8 wh0 = *(const short8*)(Wh0 + kb);
        const short8 wh1 = *(const short8*)(Wh0 + 16 * KPAD + kb);
        const short8 wh2 = *(const short8*)(Wh0 + 32 * KPAD + kb);
        const short8 wh3 = *(const short8*)(Wh0 + 48 * KPAD + kb);
        const short8 wl0 = *(const short8*)(Wl0 + kb);
        const short8 wl1 = *(const short8*)(Wl0 + 16 * KPAD + kb);
        const short8 wl2 = *(const short8*)(Wl0 + 32 * KPAD + kb);
        const short8 wl3 = *(const short8*)(Wl0 + 48 * KPAD + kb);

        acc0 = __builtin_amdgcn_mfma_f32_16x16x32_bf16(a, wh0, acc0, 0, 0, 0);
        acc1 = __builtin_amdgcn_mfma_f32_16x16x32_bf16(a, wh1, acc1, 0, 0, 0);
        acc2 = __builtin_amdgcn_mfma_f32_16x16x32_bf16(a, wh2, acc2, 0, 0, 0);
        acc3 = __builtin_amdgcn_mfma_f32_16x16x32_bf16(a, wh3, acc3, 0, 0, 0);
        acc0 = __builtin_amdgcn_mfma_f32_16x16x32_bf16(a, wl0, acc0, 0, 0, 0);
        acc1 = __builtin_amdgcn_mfma_f32_16x16x32_bf16(a, wl1, acc1, 0, 0, 0);
        acc2 = __builtin_amdgcn_mfma_f32_16x16x32_bf16(a, wl2, acc2, 0, 0, 0);
        acc3 = __builtin_amdgcn_mfma_f32_16x16x32_bf16(a, wl3, acc3, 0, 0, 0);
    }

    // C/D layout: col = lane&15, row = (lane>>4)*4 + reg  [m89-verified]
    const int ocol = lane & 15;
    const int br0 = (lane >> 4) * 4;
#pragma unroll
    for (int nb = 0; nb < 4; ++nb) {
        const int o = o0 + nb * 16 + ocol;
        if (o < OUT_DIM) {
            const float bias = fcb[o];
            const f32x4 acc = (nb == 0) ? acc0 : (nb == 1) ? acc1 : (nb == 2) ? acc2 : acc3;
#pragma unroll
            for (int r = 0; r < 4; ++r) {
                const int bi = b0 + br0 + r;
                out[(size_t)bi * OUT_DIM + o] = acc[r] + bias;
            }
        }
    }
}

extern "C" void kernel_launch(void* const* d_in, const int* in_sizes, int n_in,
                              void* d_out, int out_size, void* d_ws, size_t ws_size,
                              hipStream_t stream) {
    const float* x    = (const float*)d_in[0];
    const float* W_ih = (const float*)d_in[3];
    const float* W_hh = (const float*)d_in[4];
    const float* b_ih = (const float*)d_in[5];
    const float* b_hh = (const float*)d_in[6];
    const float* fcW  = (const float*)d_in[7];
    const float* fcb  = (const float*)d_in[8];
    float* out = (float*)d_out;

    // workspace layout (bytes):
    //   Hb : [BATCH][KPAD] bf16 = 18,874,368
    //   Whi: [OPAD][KPAD]  bf16 =  2,359,296
    //   Wlo: [OPAD][KPAD]  bf16 =  2,359,296   (total ~23.6 MB)
    unsigned short* Hb  = (unsigned short*)d_ws;
    unsigned short* Whi = (unsigned short*)((char*)d_ws + (size_t)BATCH * KPAD * 2);
    unsigned short* Wlo = (unsigned short*)((char*)d_ws + (size_t)BATCH * KPAD * 2 + (size_t)OPAD * KPAD * 2);

    lstm_kernel<<<dim3(BATCH / WAVES_PER_BLOCK), dim3(64 * WAVES_PER_BLOCK), 0, stream>>>(
        x, W_ih, W_hh, b_ih, b_hh, Hb);

    convw_kernel<<<dim3((OPAD * KPAD + 255) / 256), dim3(256), 0, stream>>>(fcW, Whi, Wlo);

    fc_kernel<<<dim3(BATCH / 64, OPAD / 64), dim3(256), 0, stream>>>(Hb, Whi, Wlo, fcb, out);
}

// Round 4
// 553.380 us; speedup vs baseline: 1.1067x; 1.0734x over previous
//
#include <hip/hip_runtime.h>

#define NUM_LAYERS 10
#define HIDDEN 5
#define SEQ 457
#define BATCH 4096
#define OUT_DIM 457
#define KD 2285            // SEQ*HIDDEN
#define KPAD 2304          // 72 * 32
#define NKT 72
#define OPAD 512

typedef __attribute__((ext_vector_type(8))) short short8;
typedef __attribute__((ext_vector_type(4))) float f32x4;

__device__ __forceinline__ float frcp(float x){ return __builtin_amdgcn_rcpf(x); }
__device__ __forceinline__ float fexp2(float x){ return __builtin_amdgcn_exp2f(x); }
__device__ __forceinline__ unsigned short f2bf(float f){
    unsigned u = __float_as_uint(f);
    u = (u + 0x7FFFu + ((u>>16)&1u)) >> 16;
    return (unsigned short)u;
}
__device__ __forceinline__ float bf2f(unsigned short h){
    return __uint_as_float(((unsigned)h) << 16);
}

// ---------------------------------------------------------------------------
// MFMA-pipelined LSTM. Block: 16 batches, 11 waves (wave l<10 = layer l,
// wave 10 = ghost x-feeder). Layer l at step s does t = s-l (466 steps).
// LDS slot C[buf][l][b] = 20 shorts: [in_hi(5) h_hi(5) in_lo(5) h_lo(5)].
// K=32 packing: k0-9 a_hi*w_hi, k10-19 a_lo*w_hi, k20-29 a_hi*w_lo, k30-31 0.
// B-frag per lane (kgrp=lane>>4, b=lane&15) = two ds_read_b64 at byte offsets
// off0={0,16,32,8}, off1={8,24,0,16} into C[buf][l][b] (k30,31 junk killed by
// zero W-pad). A-frag = weights, rows = gatecol 4j+gate; D: lane(kg,b) reg r
// = gate r of hidden j=kg for batch b. Gates prescaled: i,f,o by -log2e,
// g by 2*log2e, so sigm=rcp(1+exp2(.)), tanh=1-2*rcp(1+exp2(.)).
// ---------------------------------------------------------------------------
#define GB 16
#define NW 11
#define CSTRIDE 20                    // shorts per (l,b)
#define SLOTB (GB*CSTRIDE)            // 320 shorts per layer slot
#define BUFS (NUM_LAYERS*SLOTB)       // 3200 shorts per buffer

__global__ __launch_bounds__(64*NW) void lstm_kernel(
    const float* __restrict__ x,      // [B][SEQ][5]
    const float* __restrict__ W_ih,   // [10][20][5]
    const float* __restrict__ W_hh,   // [10][20][5]
    const float* __restrict__ b_ih,   // [10][20]
    const float* __restrict__ b_hh,   // [10][20]
    unsigned short* __restrict__ Hb)  // bf16 [BATCH][KPAD]; Hb[b][t*5+j]
{
    __shared__ unsigned short Cs[2*BUFS];   // 12.8 KB
    const int tid = threadIdx.x;
    const int wv = tid >> 6;
    const int lane = tid & 63;
    const int bBlk = blockIdx.x * GB;

    for (int i = tid; i < 2*BUFS; i += 64*NW) Cs[i] = 0;
    __syncthreads();   // B1

    // ---- persistent per-role state ----
    const int m  = lane & 15;      // A-row (gatecol) / B-row (batch) / D-col (batch)
    const int kg = lane >> 4;      // k-group; also j for D regs
    short8 wf0, wf1;
    f32x4 bias0, bias1;
    int off0 = 0, off1 = 0;
    float c0 = 0.f, c1 = 0.f;
    float xr[5];
    const float* xb = nullptr;

    if (wv < NUM_LAYERS) {
        const int l = wv;
        // Wfrag0: row = gatecol m: j=m>>2, gate=m&3
        {
            const int j = m >> 2, g = m & 3;
            const float scg = (g == 2) ? 2.8853900817779268f : -1.4426950408889634f;
            const int row = l*20 + g*5 + j;
#pragma unroll
            for (int e = 0; e < 8; ++e) {
                const int k = kg*8 + e;
                unsigned short v = 0;
                if (k < 30) {
                    const int ki = (k < 10) ? k : (k < 20) ? k-10 : k-20;
                    const float w = scg * ((ki < 5) ? W_ih[row*5+ki] : W_hh[row*5+ki-5]);
                    const unsigned short hi = f2bf(w);
                    v = (k >= 20) ? f2bf(w - bf2f(hi)) : hi;
                }
                wf0[e] = (short)v;
            }
        }
        // Wfrag1: rows 0-3 = gatecols 16-19 (j=4, gate=m), rows 4-15 zero
        {
#pragma unroll
            for (int e = 0; e < 8; ++e) {
                unsigned short v = 0;
                if (m < 4) {
                    const int g = m;
                    const float scg = (g == 2) ? 2.8853900817779268f : -1.4426950408889634f;
                    const int row = l*20 + g*5 + 4;
                    const int k = kg*8 + e;
                    if (k < 30) {
                        const int ki = (k < 10) ? k : (k < 20) ? k-10 : k-20;
                        const float w = scg * ((ki < 5) ? W_ih[row*5+ki] : W_hh[row*5+ki-5]);
                        const unsigned short hi = f2bf(w);
                        v = (k >= 20) ? f2bf(w - bf2f(hi)) : hi;
                    }
                }
                wf1[e] = (short)v;
            }
        }
        // biases (prescaled): bias0[r] = gatecol kg*4+r -> j=kg, gate=r
#pragma unroll
        for (int r = 0; r < 4; ++r) {
            const float scg = (r == 2) ? 2.8853900817779268f : -1.4426950408889634f;
            bias0[r] = scg * (b_ih[wv*20 + r*5 + kg] + b_hh[wv*20 + r*5 + kg]);
            bias1[r] = (kg == 0) ? scg * (b_ih[wv*20 + r*5 + 4] + b_hh[wv*20 + r*5 + 4]) : 0.f;
        }
        off0 = (kg==0) ? 0 : (kg==1) ? 16 : (kg==2) ? 32 : 8;
        off1 = (kg==0) ? 8 : (kg==1) ? 24 : (kg==2) ? 0 : 16;
    } else {
        // ghost wave: zero Hb pad cols, seed x[0] into buf0 slot0, prefetch x[1]
        const int b = lane & 15;
        xb = x + (size_t)(bBlk + b) * (SEQ*HIDDEN);
        for (int i = lane; i < GB*(KPAD-KD); i += 64) {
            const int bb = i / (KPAD-KD), cc = i - bb*(KPAD-KD);
            Hb[(size_t)(bBlk+bb)*KPAD + KD + cc] = 0;
        }
        if (lane < GB) {
            unsigned short* cw = &Cs[0*BUFS + 0*SLOTB + b*CSTRIDE];
#pragma unroll
            for (int i = 0; i < 5; ++i) {
                const float xv = xb[i];
                const unsigned short hi = f2bf(xv);
                cw[i] = hi;
                cw[10+i] = f2bf(xv - bf2f(hi));
            }
#pragma unroll
            for (int i = 0; i < 5; ++i) xr[i] = xb[5 + i];
        }
    }
    __syncthreads();   // B2

    for (int s = 0; s < SEQ + NUM_LAYERS - 1; ++s) {
        if (wv < NUM_LAYERS) {
            const int l = wv;
            // B-frag: two ds_read_b64 from C[s&1][l][m]
            const char* cb = (const char*)&Cs[(s&1)*BUFS + l*SLOTB + m*CSTRIDE];
            union { short8 s8; unsigned long u[2]; } bv;
            bv.u[0] = *(const unsigned long*)(cb + off0);
            bv.u[1] = *(const unsigned long*)(cb + off1);

            f32x4 d0 = __builtin_amdgcn_mfma_f32_16x16x32_bf16(wf0, bv.s8, bias0, 0, 0, 0);
            f32x4 d2 = __builtin_amdgcn_mfma_f32_16x16x32_bf16(wf1, bv.s8, bias1, 0, 0, 0);

            const float ig  = frcp(1.f + fexp2(d0[0]));
            const float fg  = frcp(1.f + fexp2(d0[1]));
            const float gg  = 1.f - 2.f*frcp(1.f + fexp2(d0[2]));
            const float og  = frcp(1.f + fexp2(d0[3]));
            const float ig1 = frcp(1.f + fexp2(d2[0]));
            const float fg1 = frcp(1.f + fexp2(d2[1]));
            const float gg1 = 1.f - 2.f*frcp(1.f + fexp2(d2[2]));
            const float og1 = frcp(1.f + fexp2(d2[3]));

            const int t = s - l;
            if (t >= 0 && t < SEQ) {
                c0 = fg*c0 + ig*gg;
                const float th0 = 1.f - 2.f*frcp(1.f + fexp2(2.8853900817779268f*c0));
                const float h0 = og*th0;
                c1 = fg1*c1 + ig1*gg1;
                const float th1 = 1.f - 2.f*frcp(1.f + fexp2(2.8853900817779268f*c1));
                const float h1 = og1*th1;

                const unsigned short h0hi = f2bf(h0);
                const unsigned short h0lo = f2bf(h0 - bf2f(h0hi));
                const unsigned short h1hi = f2bf(h1);
                const unsigned short h1lo = f2bf(h1 - bf2f(h1hi));

                unsigned short* wb = &Cs[((s+1)&1)*BUFS];
                unsigned short* myslot = wb + l*SLOTB + m*CSTRIDE;
                const int j = kg;
                myslot[5+j]  = h0hi;
                myslot[15+j] = h0lo;
                if (l < NUM_LAYERS-1) {
                    unsigned short* nx = wb + (l+1)*SLOTB + m*CSTRIDE;
                    nx[j]    = h0hi;
                    nx[10+j] = h0lo;
                    if (kg == 0) { nx[4] = h1hi; nx[14] = h1lo; }
                }
                if (kg == 0) { myslot[5+4] = h1hi; myslot[15+4] = h1lo; }
                if (l == NUM_LAYERS-1) {
                    unsigned short* hr = Hb + (size_t)(bBlk + m)*KPAD + t*5;
                    hr[j] = h0hi;
                    if (kg == 0) hr[4] = h1hi;
                }
            }
        } else {
            // ghost: write x[s+1] into buf[(s+1)&1] slot0, then load x[s+2]
            const int b = lane & 15;
            if (lane < GB) {
                const int tw = s + 1;
                if (tw < SEQ) {
                    unsigned short* cw = &Cs[((s+1)&1)*BUFS + 0*SLOTB + b*CSTRIDE];
#pragma unroll
                    for (int i = 0; i < 5; ++i) {
                        const unsigned short hi = f2bf(xr[i]);
                        cw[i] = hi;
                        cw[10+i] = f2bf(xr[i] - bf2f(hi));
                    }
                }
                int t2 = s + 2; if (t2 > SEQ-1) t2 = SEQ-1;
#pragma unroll
                for (int i = 0; i < 5; ++i) xr[i] = xb[t2*5 + i];
            }
        }
        __syncthreads();
    }
}

// ---------------------------------------------------------------------------
// fcW f32 -> bf16 hi/lo split, padded [OPAD][KPAD]
// ---------------------------------------------------------------------------
__global__ __launch_bounds__(256) void convw_kernel(
    const float* __restrict__ fcW,
    unsigned short* __restrict__ Whi,
    unsigned short* __restrict__ Wlo)
{
    const int idx = blockIdx.x * 256 + threadIdx.x;
    if (idx >= OPAD * KPAD) return;
    const int o = idx / KPAD;
    const int k = idx - o * KPAD;
    float v = 0.0f;
    if (o < OUT_DIM && k < KD) v = fcW[o * KD + k];
    const unsigned short hi = f2bf(v);
    Whi[idx] = hi;
    Wlo[idx] = f2bf(v - bf2f(hi));
}

// ---------------------------------------------------------------------------
// FC: bf16 MFMA, register double-buffer prefetch of next k-tile.
// ---------------------------------------------------------------------------
__global__ __launch_bounds__(256) void fc_kernel(
    const unsigned short* __restrict__ Hb,    // [BATCH][KPAD]
    const unsigned short* __restrict__ Whi,   // [OPAD][KPAD]
    const unsigned short* __restrict__ Wlo,   // [OPAD][KPAD]
    const float* __restrict__ fcb,
    float* __restrict__ out)                  // [BATCH][OUT_DIM]
{
    const int lane = threadIdx.x & 63;
    const int w = threadIdx.x >> 6;
    const int b0 = blockIdx.x * 64 + w * 16;
    const int o0 = blockIdx.y * 64;
    const int row = lane & 15;
    const int kq = (lane >> 4) * 8;

    const unsigned short* Ha  = Hb  + (size_t)(b0 + row) * KPAD + kq;
    const unsigned short* Wh0 = Whi + (size_t)(o0 + row) * KPAD + kq;
    const unsigned short* Wl0 = Wlo + (size_t)(o0 + row) * KPAD + kq;

    f32x4 acc0 = {0.f,0.f,0.f,0.f}, acc1 = acc0, acc2 = acc0, acc3 = acc0;

    short8 a_c   = *(const short8*)(Ha);
    short8 wh0_c = *(const short8*)(Wh0);
    short8 wh1_c = *(const short8*)(Wh0 + 16*KPAD);
    short8 wh2_c = *(const short8*)(Wh0 + 32*KPAD);
    short8 wh3_c = *(const short8*)(Wh0 + 48*KPAD);
    short8 wl0_c = *(const short8*)(Wl0);
    short8 wl1_c = *(const short8*)(Wl0 + 16*KPAD);
    short8 wl2_c = *(const short8*)(Wl0 + 32*KPAD);
    short8 wl3_c = *(const short8*)(Wl0 + 48*KPAD);

    for (int kk = 0; kk < NKT; ++kk) {
        const int kb = (kk+1 < NKT) ? (kk+1)*32 : kk*32;
        const short8 a_n   = *(const short8*)(Ha  + kb);
        const short8 wh0_n = *(const short8*)(Wh0 + kb);
        const short8 wh1_n = *(const short8*)(Wh0 + 16*KPAD + kb);
        const short8 wh2_n = *(const short8*)(Wh0 + 32*KPAD + kb);
        const short8 wh3_n = *(const short8*)(Wh0 + 48*KPAD + kb);
        const short8 wl0_n = *(const short8*)(Wl0 + kb);
        const short8 wl1_n = *(const short8*)(Wl0 + 16*KPAD + kb);
        const short8 wl2_n = *(const short8*)(Wl0 + 32*KPAD + kb);
        const short8 wl3_n = *(const short8*)(Wl0 + 48*KPAD + kb);

        acc0 = __builtin_amdgcn_mfma_f32_16x16x32_bf16(a_c, wh0_c, acc0, 0,0,0);
        acc1 = __builtin_amdgcn_mfma_f32_16x16x32_bf16(a_c, wh1_c, acc1, 0,0,0);
        acc2 = __builtin_amdgcn_mfma_f32_16x16x32_bf16(a_c, wh2_c, acc2, 0,0,0);
        acc3 = __builtin_amdgcn_mfma_f32_16x16x32_bf16(a_c, wh3_c, acc3, 0,0,0);
        acc0 = __builtin_amdgcn_mfma_f32_16x16x32_bf16(a_c, wl0_c, acc0, 0,0,0);
        acc1 = __builtin_amdgcn_mfma_f32_16x16x32_bf16(a_c, wl1_c, acc1, 0,0,0);
        acc2 = __builtin_amdgcn_mfma_f32_16x16x32_bf16(a_c, wl2_c, acc2, 0,0,0);
        acc3 = __builtin_amdgcn_mfma_f32_16x16x32_bf16(a_c, wl3_c, acc3, 0,0,0);

        a_c = a_n;
        wh0_c = wh0_n; wh1_c = wh1_n; wh2_c = wh2_n; wh3_c = wh3_n;
        wl0_c = wl0_n; wl1_c = wl1_n; wl2_c = wl2_n; wl3_c = wl3_n;
    }

    const int ocol = lane & 15;
    const int br0 = (lane >> 4) * 4;
#pragma unroll
    for (int nb = 0; nb < 4; ++nb) {
        const int o = o0 + nb * 16 + ocol;
        if (o < OUT_DIM) {
            const float bias = fcb[o];
            const f32x4 acc = (nb == 0) ? acc0 : (nb == 1) ? acc1 : (nb == 2) ? acc2 : acc3;
#pragma unroll
            for (int r = 0; r < 4; ++r) {
                const int bi = b0 + br0 + r;
                out[(size_t)bi * OUT_DIM + o] = acc[r] + bias;
            }
        }
    }
}

extern "C" void kernel_launch(void* const* d_in, const int* in_sizes, int n_in,
                              void* d_out, int out_size, void* d_ws, size_t ws_size,
                              hipStream_t stream) {
    const float* x    = (const float*)d_in[0];
    const float* W_ih = (const float*)d_in[3];
    const float* W_hh = (const float*)d_in[4];
    const float* b_ih = (const float*)d_in[5];
    const float* b_hh = (const float*)d_in[6];
    const float* fcW  = (const float*)d_in[7];
    const float* fcb  = (const float*)d_in[8];
    float* out = (float*)d_out;

    unsigned short* Hb  = (unsigned short*)d_ws;
    unsigned short* Whi = (unsigned short*)((char*)d_ws + (size_t)BATCH * KPAD * 2);
    unsigned short* Wlo = (unsigned short*)((char*)d_ws + (size_t)BATCH * KPAD * 2 + (size_t)OPAD * KPAD * 2);

    lstm_kernel<<<dim3(BATCH / GB), dim3(64 * NW), 0, stream>>>(
        x, W_ih, W_hh, b_ih, b_hh, Hb);

    convw_kernel<<<dim3((OPAD * KPAD + 255) / 256), dim3(256), 0, stream>>>(fcW, Whi, Wlo);

    fc_kernel<<<dim3(BATCH / 64, OPAD / 64), dim3(256), 0, stream>>>(Hb, Whi, Wlo, fcb, out);
}

// Round 6
// 488.899 us; speedup vs baseline: 1.2526x; 1.1319x over previous
//
#include <hip/hip_runtime.h>

#define NUM_LAYERS 10
#define HIDDEN 5
#define SEQ 457
#define BATCH 4096
#define OUT_DIM 457
#define KD 2285
#define KPAD 2304          // 72*32
#define NKT 72
#define OPAD 512

typedef __attribute__((ext_vector_type(8))) short short8;
typedef __attribute__((ext_vector_type(4))) float f32x4;
typedef unsigned long long ull;
typedef unsigned short ushort;

__device__ __forceinline__ float frcp(float x){ return __builtin_amdgcn_rcpf(x); }
__device__ __forceinline__ float fexp2(float x){ return __builtin_amdgcn_exp2f(x); }
__device__ __forceinline__ ushort f2bf(float f){
    unsigned u = __float_as_uint(f);
    u = (u + 0x7FFFu + ((u>>16)&1u)) >> 16;
    return (ushort)u;
}
__device__ __forceinline__ float bf2f(ushort h){ return __uint_as_float(((unsigned)h) << 16); }
// D.b16[0]=bf16(a), D.b16[1]=bf16(b)  (RNE)
__device__ __forceinline__ unsigned cvtpk(float a, float b){
    unsigned r;
    asm("v_cvt_pk_bf16_f32 %0, %1, %2" : "=v"(r) : "v"(a), "v"(b));
    return r;
}
__device__ __forceinline__ void act4(const f32x4 d, float& i_, float& f_, float& g_, float& o_){
    i_ = frcp(1.f + fexp2(d[0]));
    f_ = frcp(1.f + fexp2(d[1]));
    g_ = 1.f - 2.f*frcp(1.f + fexp2(d[2]));
    o_ = frcp(1.f + fexp2(d[3]));
}
__device__ __forceinline__ float tanhc(float c){ return 1.f - 2.f*frcp(1.f + fexp2(2.8853900817779268f*c)); }

// ---------------------------------------------------------------------------
// LSTM: 16 batches/block, 11 waves (10 layer waves + ghost x-feeder).
// 2 timesteps per barrier: layer l at iteration s computes t0=2(s-l), t1=t0+1.
// t1's h-operand = own h(t0), exchanged via same-wave LDS round trip (lgkm).
// LDS slot (buf,l,b) = 40 shorts: E[in_hi5 h_hi5 in_lo5 h_lo5] O[same].
// H output written directly in packed MFMA-fragment layout HbP.
// ---------------------------------------------------------------------------
#define GB 16
#define NW 11
#define BUFS 6400           // shorts per buffer (10*16*40)

__global__ __launch_bounds__(64*NW) void lstm_kernel(
    const float* __restrict__ x,      // [B][SEQ][5]
    const float* __restrict__ W_ih,   // [10][20][5]
    const float* __restrict__ W_hh,
    const float* __restrict__ b_ih,
    const float* __restrict__ b_hh,
    ushort* __restrict__ HbP)         // packed [256 bg][72 kk][64 L][8]
{
    __shared__ ull CsQ[3200];         // 25.6 KB
    ushort* Cs = (ushort*)CsQ;
    const int tid = threadIdx.x;
    const int lane = tid & 63;
    const int lS = __builtin_amdgcn_readfirstlane(tid >> 6);
    const int bg = blockIdx.x;
    const int hbBase = bg * (NKT*512);   // shorts

    for (int i = tid; i < 3200; i += 64*NW) CsQ[i] = 0;
    __syncthreads();

    const int m  = lane & 15;
    const int kg = lane >> 4;

    short8 wf0{}, wf1{};
    f32x4 bias0{}, bias1{};
    float c0 = 0.f, c4 = 0.f;
    float xr0=0,xr1=0,xr2=0,xr3=0,xr4=0;
    const float* xb2 = nullptr;
    const int half = lane >> 4;       // ghost: 0/1 (lanes<32)
    const int gb = lane & 15;

    const char* rd0 = nullptr; const char* rd1 = nullptr;
    ushort* myP = nullptr; ushort* j4P = nullptr;
    char* gw = nullptr;

    if (lS < NUM_LAYERS) {
        const int l = lS;
        { // wf0: rows = gatecol m (j=m>>2, g=m&3)
            const int j = m >> 2, g = m & 3;
            const float scg = (g == 2) ? 2.8853900817779268f : -1.4426950408889634f;
            const int row = l*20 + g*5 + j;
#pragma unroll
            for (int e = 0; e < 8; ++e) {
                const int k = kg*8 + e;
                ushort v = 0;
                if (k < 30) {
                    const int ki = (k < 10) ? k : (k < 20) ? k-10 : k-20;
                    const float w = scg * ((ki < 5) ? W_ih[row*5+ki] : W_hh[row*5+ki-5]);
                    const ushort hi = f2bf(w);
                    v = (k >= 20) ? f2bf(w - bf2f(hi)) : hi;
                }
                wf0[e] = (short)v;
            }
        }
        { // wf1: rows 0-3 = j=4 gates
#pragma unroll
            for (int e = 0; e < 8; ++e) {
                ushort v = 0;
                if (m < 4) {
                    const int g = m;
                    const float scg = (g == 2) ? 2.8853900817779268f : -1.4426950408889634f;
                    const int row = l*20 + g*5 + 4;
                    const int k = kg*8 + e;
                    if (k < 30) {
                        const int ki = (k < 10) ? k : (k < 20) ? k-10 : k-20;
                        const float w = scg * ((ki < 5) ? W_ih[row*5+ki] : W_hh[row*5+ki-5]);
                        const ushort hi = f2bf(w);
                        v = (k >= 20) ? f2bf(w - bf2f(hi)) : hi;
                    }
                }
                wf1[e] = (short)v;
            }
        }
#pragma unroll
        for (int r = 0; r < 4; ++r) {
            const float scg = (r == 2) ? 2.8853900817779268f : -1.4426950408889634f;
            bias0[r] = scg * (b_ih[l*20 + r*5 + kg] + b_hh[l*20 + r*5 + kg]);
            bias1[r] = (kg == 0) ? scg * (b_ih[l*20 + r*5 + 4] + b_hh[l*20 + r*5 + 4]) : 0.f;
        }
        const int off0 = (kg==0) ? 0 : (kg==1) ? 16 : (kg==2) ? 32 : 8;
        const int off1 = (kg==0) ? 8 : (kg==1) ? 24 : (kg==2) ? 0 : 16;
        const int slotB = (l*16 + m) * 80;        // bytes
        rd0 = (const char*)Cs + slotB + off0;
        rd1 = (const char*)Cs + slotB + off1;
        myP = Cs + (l*16 + m)*40 + kg;
        j4P = Cs + (l*16 + m)*40;
    } else {
        // ghost wave
        if (lane < 32) {
            xb2 = x + (size_t)(bg*GB + gb) * (SEQ*HIDDEN);
            gw = (char*)Cs + gb*80 + half*40;
        }
        // zero the kk=71 slab of this bg (pad cols stay 0)
        ull* slab = (ull*)(HbP + hbBase + 71*512);
        slab[lane] = 0; slab[lane + 64] = 0;
    }
    __syncthreads();

    if (lS == NUM_LAYERS && lane < 32) {
        // seed buf0: rows 0 (E) and 1 (O) of layer 0; prefetch rows 2,3
        float v0 = xb2[half*5+0], v1 = xb2[half*5+1], v2 = xb2[half*5+2],
              v3 = xb2[half*5+3], v4 = xb2[half*5+4];
        unsigned p01 = cvtpk(v0,v1), p23 = cvtpk(v2,v3);
        ushort p4 = f2bf(v4);
        float l0 = v0 - __uint_as_float(p01<<16), l1 = v1 - __uint_as_float(p01 & 0xFFFF0000u);
        float l2 = v2 - __uint_as_float(p23<<16), l3 = v3 - __uint_as_float(p23 & 0xFFFF0000u);
        float l4 = v4 - bf2f(p4);
        unsigned q01 = cvtpk(l0,l1), q23 = cvtpk(l2,l3);
        *(unsigned*)(gw + 0)  = p01;
        *(unsigned*)(gw + 4)  = p23;
        *(ushort*)  (gw + 8)  = p4;
        *(unsigned*)(gw + 20) = q01;
        *(unsigned*)(gw + 24) = q23;
        *(ushort*)  (gw + 28) = f2bf(l4);
        xr0 = xb2[(2+half)*5+0]; xr1 = xb2[(2+half)*5+1]; xr2 = xb2[(2+half)*5+2];
        xr3 = xb2[(2+half)*5+3]; xr4 = xb2[(2+half)*5+4];
    }
    __syncthreads();

    int s = 0;
    auto cell = [&](int PP) {
        const int WP = 1 - PP;
        const int t0 = 2*(s - lS);
        const bool a0 = (t0 >= 0) & (t0 <= SEQ-1);
        const bool a1 = (t0 >= 0) & (t0 <  SEQ-1);
        union { short8 v; ull q[2]; } bf;
        bf.q[0] = *(const ull*)(rd0 + PP*12800);
        bf.q[1] = *(const ull*)(rd1 + PP*12800);
        f32x4 d0 = __builtin_amdgcn_mfma_f32_16x16x32_bf16(wf0, bf.v, bias0, 0,0,0);
        f32x4 d4 = __builtin_amdgcn_mfma_f32_16x16x32_bf16(wf1, bf.v, bias1, 0,0,0);
        float ig,fg,gg,og, i4,f4,g4,o4;
        act4(d0, ig,fg,gg,og);
        act4(d4, i4,f4,g4,o4);
        if (a0) {
            c0 = fg*c0 + ig*gg;
            const float h = og * tanhc(c0);
            c4 = f4*c4 + i4*g4;
            const float h4 = o4 * tanhc(c4);
            const unsigned ph = cvtpk(h, h4);
            const unsigned pl = cvtpk(h - __uint_as_float(ph<<16),
                                      h4 - __uint_as_float(ph & 0xFFFF0000u));
            myP[PP*BUFS + 25] = (ushort)ph;          // own O.h (for t1 frag)
            myP[PP*BUFS + 35] = (ushort)pl;
            if (kg == 0) { j4P[PP*BUFS + 29] = (ushort)(ph>>16); j4P[PP*BUFS + 39] = (ushort)(pl>>16); }
            if (lS < NUM_LAYERS-1) {
                myP[WP*BUFS + 640] = (ushort)ph;     // next layer E.in
                myP[WP*BUFS + 650] = (ushort)pl;
                if (kg == 0) { j4P[WP*BUFS + 644] = (ushort)(ph>>16); j4P[WP*BUFS + 654] = (ushort)(pl>>16); }
            } else {
                const int k = t0*5 + kg;
                HbP[hbBase + (k>>5)*512 + ((k>>3)&3)*128 + m*8 + (k&7)] = (ushort)ph;
                if (kg == 0) {
                    const int k4 = t0*5 + 4;
                    HbP[hbBase + (k4>>5)*512 + ((k4>>3)&3)*128 + m*8 + (k4&7)] = (ushort)(ph>>16);
                }
            }
        }
        // t1: O fragment (reads own just-written h(t0) — same-wave lgkm order)
        bf.q[0] = *(const ull*)(rd0 + PP*12800 + 40);
        bf.q[1] = *(const ull*)(rd1 + PP*12800 + 40);
        d0 = __builtin_amdgcn_mfma_f32_16x16x32_bf16(wf0, bf.v, bias0, 0,0,0);
        d4 = __builtin_amdgcn_mfma_f32_16x16x32_bf16(wf1, bf.v, bias1, 0,0,0);
        act4(d0, ig,fg,gg,og);
        act4(d4, i4,f4,g4,o4);
        if (a1) {
            c0 = fg*c0 + ig*gg;
            const float h = og * tanhc(c0);
            c4 = f4*c4 + i4*g4;
            const float h4 = o4 * tanhc(c4);
            const unsigned ph = cvtpk(h, h4);
            const unsigned pl = cvtpk(h - __uint_as_float(ph<<16),
                                      h4 - __uint_as_float(ph & 0xFFFF0000u));
            myP[WP*BUFS + 5]  = (ushort)ph;          // own E.h (h_prev next iter)
            myP[WP*BUFS + 15] = (ushort)pl;
            if (kg == 0) { j4P[WP*BUFS + 9] = (ushort)(ph>>16); j4P[WP*BUFS + 19] = (ushort)(pl>>16); }
            if (lS < NUM_LAYERS-1) {
                myP[WP*BUFS + 660] = (ushort)ph;     // next layer O.in
                myP[WP*BUFS + 670] = (ushort)pl;
                if (kg == 0) { j4P[WP*BUFS + 664] = (ushort)(ph>>16); j4P[WP*BUFS + 674] = (ushort)(pl>>16); }
            } else {
                const int k = (t0+1)*5 + kg;
                HbP[hbBase + (k>>5)*512 + ((k>>3)&3)*128 + m*8 + (k&7)] = (ushort)ph;
                if (kg == 0) {
                    const int k4 = (t0+1)*5 + 4;
                    HbP[hbBase + (k4>>5)*512 + ((k4>>3)&3)*128 + m*8 + (k4&7)] = (ushort)(ph>>16);
                }
            }
        }
    };
    auto ghost = [&](int PP) {
        const int WP = 1 - PP;
        if (lane < 32) {
            const int tw = 2*s + 2 + half;
            if (tw < SEQ) {
                unsigned p01 = cvtpk(xr0,xr1), p23 = cvtpk(xr2,xr3);
                ushort p4 = f2bf(xr4);
                float l0 = xr0 - __uint_as_float(p01<<16), l1 = xr1 - __uint_as_float(p01 & 0xFFFF0000u);
                float l2 = xr2 - __uint_as_float(p23<<16), l3 = xr3 - __uint_as_float(p23 & 0xFFFF0000u);
                float l4 = xr4 - bf2f(p4);
                unsigned q01 = cvtpk(l0,l1), q23 = cvtpk(l2,l3);
                *(unsigned*)(gw + WP*12800 + 0)  = p01;
                *(unsigned*)(gw + WP*12800 + 4)  = p23;
                *(ushort*)  (gw + WP*12800 + 8)  = p4;
                *(unsigned*)(gw + WP*12800 + 20) = q01;
                *(unsigned*)(gw + WP*12800 + 24) = q23;
                *(ushort*)  (gw + WP*12800 + 28) = f2bf(l4);
            }
            int tn = 2*s + 4 + half; if (tn > SEQ-1) tn = SEQ-1;
            xr0 = xb2[tn*5+0]; xr1 = xb2[tn*5+1]; xr2 = xb2[tn*5+2];
            xr3 = xb2[tn*5+3]; xr4 = xb2[tn*5+4];
        }
    };

    for (int it = 0; it < 119; ++it) {
        if (lS < NUM_LAYERS) cell(0); else ghost(0);
        __syncthreads(); ++s;
        if (lS < NUM_LAYERS) cell(1); else ghost(1);
        __syncthreads(); ++s;
    }
}

// ---------------------------------------------------------------------------
// fcW -> packed bf16 hi/lo fragments: [og(32)][kk(72)][L(64)][e(8)]
// ---------------------------------------------------------------------------
__global__ __launch_bounds__(256) void convw_kernel(
    const float* __restrict__ fcW,
    ushort* __restrict__ WhiP,
    ushort* __restrict__ WloP)
{
    const int tidg = blockIdx.x * 256 + threadIdx.x;
    if (tidg >= 32*NKT*64) return;
    const int L  = tidg & 63;
    const int kk = (tidg >> 6) % NKT;
    const int og = tidg / (64*NKT);
    const int o = og*16 + (L & 15);
    const int kb = kk*32 + ((L >> 4) << 3);
    short8 hi8{}, lo8{};
#pragma unroll
    for (int e = 0; e < 8; ++e) {
        const int k = kb + e;
        float v = 0.f;
        if (o < OUT_DIM && k < KD) v = fcW[(size_t)o*KD + k];
        const ushort hi = f2bf(v);
        hi8[e] = (short)hi;
        lo8[e] = (short)f2bf(v - bf2f(hi));
    }
    *(short8*)&WhiP[(size_t)tidg*8] = hi8;
    *(short8*)&WloP[(size_t)tidg*8] = lo8;
}

// ---------------------------------------------------------------------------
// FC: all operands in packed fragment layout -> every load lane-coalesced.
// Wave = one 16-batch group x 64 o-cols; W hi+lo -> 8 MFMA/k-iter.
// ---------------------------------------------------------------------------
__global__ __launch_bounds__(256) void fc_kernel(
    const ushort* __restrict__ HbP,    // [256][72][64][8]
    const ushort* __restrict__ WhiP,   // [32][72][64][8]
    const ushort* __restrict__ WloP,
    const float* __restrict__ fcb,
    float* __restrict__ out)           // [BATCH][OUT_DIM]
{
    const int lane = threadIdx.x & 63;
    const int w = threadIdx.x >> 6;
    const int bgi = blockIdx.x*4 + w;          // 0..255
    const int ogB = blockIdx.y*4;              // 0..28
    const ushort* Ap  = HbP  + (size_t)bgi*(NKT*512) + lane*8;
    const ushort* Wh0 = WhiP + (size_t)(ogB+0)*(NKT*512) + lane*8;
    const ushort* Wh1 = WhiP + (size_t)(ogB+1)*(NKT*512) + lane*8;
    const ushort* Wh2 = WhiP + (size_t)(ogB+2)*(NKT*512) + lane*8;
    const ushort* Wh3 = WhiP + (size_t)(ogB+3)*(NKT*512) + lane*8;
    const ushort* Wl0 = WloP + (size_t)(ogB+0)*(NKT*512) + lane*8;
    const ushort* Wl1 = WloP + (size_t)(ogB+1)*(NKT*512) + lane*8;
    const ushort* Wl2 = WloP + (size_t)(ogB+2)*(NKT*512) + lane*8;
    const ushort* Wl3 = WloP + (size_t)(ogB+3)*(NKT*512) + lane*8;

    f32x4 acc0{}, acc1{}, acc2{}, acc3{};

    short8 a_c   = *(const short8*)(Ap);
    short8 wh0_c = *(const short8*)(Wh0);
    short8 wh1_c = *(const short8*)(Wh1);
    short8 wh2_c = *(const short8*)(Wh2);
    short8 wh3_c = *(const short8*)(Wh3);
    short8 wl0_c = *(const short8*)(Wl0);
    short8 wl1_c = *(const short8*)(Wl1);
    short8 wl2_c = *(const short8*)(Wl2);
    short8 wl3_c = *(const short8*)(Wl3);

    for (int kk = 0; kk < NKT; ++kk) {
        const int kb = (kk+1 < NKT) ? (kk+1)*512 : kk*512;
        const short8 a_n   = *(const short8*)(Ap  + kb);
        const short8 wh0_n = *(const short8*)(Wh0 + kb);
        const short8 wh1_n = *(const short8*)(Wh1 + kb);
        const short8 wh2_n = *(const short8*)(Wh2 + kb);
        const short8 wh3_n = *(const short8*)(Wh3 + kb);
        const short8 wl0_n = *(const short8*)(Wl0 + kb);
        const short8 wl1_n = *(const short8*)(Wl1 + kb);
        const short8 wl2_n = *(const short8*)(Wl2 + kb);
        const short8 wl3_n = *(const short8*)(Wl3 + kb);

        acc0 = __builtin_amdgcn_mfma_f32_16x16x32_bf16(a_c, wh0_c, acc0, 0,0,0);
        acc1 = __builtin_amdgcn_mfma_f32_16x16x32_bf16(a_c, wh1_c, acc1, 0,0,0);
        acc2 = __builtin_amdgcn_mfma_f32_16x16x32_bf16(a_c, wh2_c, acc2, 0,0,0);
        acc3 = __builtin_amdgcn_mfma_f32_16x16x32_bf16(a_c, wh3_c, acc3, 0,0,0);
        acc0 = __builtin_amdgcn_mfma_f32_16x16x32_bf16(a_c, wl0_c, acc0, 0,0,0);
        acc1 = __builtin_amdgcn_mfma_f32_16x16x32_bf16(a_c, wl1_c, acc1, 0,0,0);
        acc2 = __builtin_amdgcn_mfma_f32_16x16x32_bf16(a_c, wl2_c, acc2, 0,0,0);
        acc3 = __builtin_amdgcn_mfma_f32_16x16x32_bf16(a_c, wl3_c, acc3, 0,0,0);

        a_c = a_n;
        wh0_c = wh0_n; wh1_c = wh1_n; wh2_c = wh2_n; wh3_c = wh3_n;
        wl0_c = wl0_n; wl1_c = wl1_n; wl2_c = wl2_n; wl3_c = wl3_n;
    }

    const int ocol = lane & 15;
    const int br0 = (lane >> 4) * 4;
    const int b0 = bgi * 16;
#pragma unroll
    for (int nb = 0; nb < 4; ++nb) {
        const int o = (ogB + nb)*16 + ocol;
        if (o < OUT_DIM) {
            const float bias = fcb[o];
            const f32x4 acc = (nb==0) ? acc0 : (nb==1) ? acc1 : (nb==2) ? acc2 : acc3;
#pragma unroll
            for (int r = 0; r < 4; ++r) {
                out[(size_t)(b0 + br0 + r)*OUT_DIM + o] = acc[r] + bias;
            }
        }
    }
}

extern "C" void kernel_launch(void* const* d_in, const int* in_sizes, int n_in,
                              void* d_out, int out_size, void* d_ws, size_t ws_size,
                              hipStream_t stream) {
    const float* x    = (const float*)d_in[0];
    const float* W_ih = (const float*)d_in[3];
    const float* W_hh = (const float*)d_in[4];
    const float* b_ih = (const float*)d_in[5];
    const float* b_hh = (const float*)d_in[6];
    const float* fcW  = (const float*)d_in[7];
    const float* fcb  = (const float*)d_in[8];
    float* out = (float*)d_out;

    // ws: HbP 18.87MB | WhiP 2.36MB | WloP 2.36MB
    ushort* HbP  = (ushort*)d_ws;
    ushort* WhiP = (ushort*)((char*)d_ws + (size_t)256*NKT*512*2);
    ushort* WloP = (ushort*)((char*)d_ws + (size_t)256*NKT*512*2 + (size_t)32*NKT*512*2);

    lstm_kernel<<<dim3(BATCH/GB), dim3(64*NW), 0, stream>>>(
        x, W_ih, W_hh, b_ih, b_hh, HbP);

    convw_kernel<<<dim3((32*NKT*64 + 255)/256), dim3(256), 0, stream>>>(fcW, WhiP, WloP);

    fc_kernel<<<dim3(64, 8), dim3(256), 0, stream>>>(HbP, WhiP, WloP, fcb, out);
}